// Round 8
// baseline (344.993 us; speedup 1.0000x reference)
//
#include <hip/hip_runtime.h>
#include <hip/hip_bf16.h>

// Problem constants: B=4, S=2048, D=1024, H=16, dk=64
#define SEQ   2048
#define NB    4
#define NH    16
#define DK    64
#define DM    1024
#define MROWS (NB * SEQ)   // 8192
#define WEL   (DM * DM)

typedef __bf16 bf16_t;
typedef __bf16 bf16x8 __attribute__((ext_vector_type(8)));
typedef __bf16 bf16x4 __attribute__((ext_vector_type(4)));
typedef float  f32x4  __attribute__((ext_vector_type(4)));

#define MFMA16(a, b, c) __builtin_amdgcn_mfma_f32_16x16x32_bf16((a), (b), (c), 0, 0, 0)

// async global->LDS, 16B per lane; LDS dest wave-uniform, HW scatters +lane*16
__device__ __forceinline__ void gl2lds16(const bf16_t* g, bf16_t* l) {
    __builtin_amdgcn_global_load_lds(
        (const __attribute__((address_space(1))) unsigned int*)g,
        (__attribute__((address_space(3))) unsigned int*)l, 16, 0, 0);
}

#define BAR()   __builtin_amdgcn_s_barrier()
#define SCB()   __builtin_amdgcn_sched_barrier(0)
#define LGK0()  asm volatile("s_waitcnt lgkmcnt(0)")
#define LGK8()  asm volatile("s_waitcnt lgkmcnt(8)")
#define VMC(N)  asm volatile("s_waitcnt vmcnt(" #N ")")

// ---------------------------------------------------------------------------
// Fused preprocessing: cvt (blocks 0..8191) + 4x weight transpose
// (8192..12287) + rope table (12288..12543).  One launch instead of six.
// ---------------------------------------------------------------------------
__global__ __launch_bounds__(256) void prep_kernel(
    const float* __restrict__ x,
    const float* __restrict__ Wq, const float* __restrict__ Wk,
    const float* __restrict__ Wv, const float* __restrict__ Wo,
    bf16_t* __restrict__ xb, bf16_t* __restrict__ Wqkvt,
    bf16_t* __restrict__ Wot, float2* __restrict__ rope)
{
    __shared__ float T[32][33];
    const int bid = blockIdx.x;
    const int tid = threadIdx.x;

    if (bid < 8192) {                       // fp32 -> bf16 conversion of x
        const int i = (bid * 256 + tid) * 4;
        const float4 v = *(const float4*)(x + i);
        bf16x4 o;
        o[0] = (bf16_t)v.x; o[1] = (bf16_t)v.y;
        o[2] = (bf16_t)v.z; o[3] = (bf16_t)v.w;
        *(bf16x4*)(xb + i) = o;
    } else if (bid < 12288) {               // weight transpose + cast
        const int wb = bid - 8192;
        const int w  = wb >> 10;            // which matrix
        const int b10 = wb & 1023;
        const float* W = (w == 0) ? Wq : (w == 1) ? Wk : (w == 2) ? Wv : Wo;
        bf16_t* Wt = (w == 3) ? Wot : Wqkvt + (size_t)w * WEL;
        const int tk0 = (b10 >> 5) << 5;
        const int tn0 = (b10 & 31) << 5;
        const int r = tid >> 5, c = tid & 31;
#pragma unroll
        for (int i = 0; i < 4; ++i)
            T[r + i * 8][c] = W[(size_t)(tk0 + r + i * 8) * DM + tn0 + c];
        __syncthreads();
#pragma unroll
        for (int i = 0; i < 4; ++i)
            Wt[(size_t)(tn0 + r + i * 8) * DM + tk0 + c] = (bf16_t)T[c][r + i * 8];
    } else {                                // rope table
        const int idx = (bid - 12288) * 256 + tid;
        const int s = idx >> 5, i = idx & 31;
        const float freq = powf(10000.0f, -(float)i / 32.0f);
        const float a = (float)s * freq;
        rope[idx] = make_float2(cosf(a), sinf(a));
    }
}

// ---------------------------------------------------------------------------
// 256x256xBK64 8-phase K-loop (unchanged — QKV structure plateau).
// ---------------------------------------------------------------------------
template<bool TR>
__device__ __forceinline__ void kloop(
    const bf16_t* __restrict__ Xp, const bf16_t* __restrict__ Wp,
    bf16_t* L, int tid, f32x4 (&acc)[8][4])
{
    const int lane = tid & 63;
    const int wave = tid >> 6;
    const int wm   = wave >> 2;
    const int wn   = wave & 3;
    const int lrow = lane & 15;
    const int lcol = (lane >> 4) << 3;

    bf16_t* const AR = L;
    bf16_t* const BR = L + 32768;

    const bf16_t* pA0 = Xp + (size_t)(wave * 16 + lrow) * DM + lcol;
    const bf16_t* pA1 = pA0 + (size_t)128 * DM;
    const bf16_t* pB0 = Wp + (size_t)(wave * 16 + lrow) * DM + lcol;
    const bf16_t* pB1 = pB0 + (size_t)128 * DM;

    bf16_t* const adst = AR + wave * 1024;
    bf16_t* const bdst = BR + wave * 1024;

    const bf16_t* const Ard = AR + wm * 8192;
    const bf16_t* const Brd = BR + wn * 4096;

    bf16x8 a[2][2], bc[4][2];

#define RD_A(BUF, Q)                                                          \
    a[0][0] = *(const bf16x8*)(Ard + (BUF) + (2*(Q)+0)*1024 + lane*8);        \
    a[0][1] = *(const bf16x8*)(Ard + (BUF) + (2*(Q)+0)*1024 + 512 + lane*8);  \
    a[1][0] = *(const bf16x8*)(Ard + (BUF) + (2*(Q)+1)*1024 + lane*8);        \
    a[1][1] = *(const bf16x8*)(Ard + (BUF) + (2*(Q)+1)*1024 + 512 + lane*8);

#define RD_B(BUF, NF)                                                         \
    bc[NF][0] = *(const bf16x8*)(Brd + (BUF) + (NF)*1024 + lane*8);           \
    bc[NF][1] = *(const bf16x8*)(Brd + (BUF) + (NF)*1024 + 512 + lane*8);

#define ST_A(BUF, H, C)                                                       \
    gl2lds16(((H) ? pA1 : pA0) + (C),      adst + (BUF) + (H)*8192);          \
    gl2lds16(((H) ? pA1 : pA0) + (C) + 32, adst + (BUF) + (H)*8192 + 512);

#define ST_B(BUF, H, C)                                                       \
    gl2lds16(((H) ? pB1 : pB0) + (C),      bdst + (BUF) + (H)*8192);          \
    gl2lds16(((H) ? pB1 : pB0) + (C) + 32, bdst + (BUF) + (H)*8192 + 512);

#define QMMA(Q)                                                               \
    __builtin_amdgcn_s_setprio(1);                                            \
    _Pragma("unroll")                                                         \
    for (int nf = 0; nf < 4; ++nf) {                                          \
        if (TR) {                                                             \
            acc[2*(Q)][nf]   = MFMA16(bc[nf][0], a[0][0], acc[2*(Q)][nf]);    \
            acc[2*(Q)][nf]   = MFMA16(bc[nf][1], a[0][1], acc[2*(Q)][nf]);    \
            acc[2*(Q)+1][nf] = MFMA16(bc[nf][0], a[1][0], acc[2*(Q)+1][nf]);  \
            acc[2*(Q)+1][nf] = MFMA16(bc[nf][1], a[1][1], acc[2*(Q)+1][nf]);  \
        } else {                                                              \
            acc[2*(Q)][nf]   = MFMA16(a[0][0], bc[nf][0], acc[2*(Q)][nf]);    \
            acc[2*(Q)][nf]   = MFMA16(a[0][1], bc[nf][1], acc[2*(Q)][nf]);    \
            acc[2*(Q)+1][nf] = MFMA16(a[1][0], bc[nf][0], acc[2*(Q)+1][nf]);  \
            acc[2*(Q)+1][nf] = MFMA16(a[1][1], bc[nf][1], acc[2*(Q)+1][nf]);  \
        }                                                                     \
    }                                                                         \
    __builtin_amdgcn_s_setprio(0);

    ST_B(0, 0, 0)      ST_B(0, 1, 0)
    ST_A(0, 0, 0)      ST_A(0, 1, 0)
    ST_B(16384, 0, 64) ST_B(16384, 1, 64)
    VMC(4);
    BAR();

    for (int it = 0; it < 8; ++it) {
        const bool lst = (it == 7);

        RD_A(0, 0) RD_B(0, 0) RD_B(0, 1) RD_B(0, 2) RD_B(0, 3)
        ST_A(16384, 0, 64) ST_A(16384, 1, 64)
        LGK8();
        BAR(); LGK0(); SCB();
        QMMA(0)
        BAR();

        RD_A(0, 1)
        if (!lst) { ST_B(0, 0, 128) }
        BAR(); LGK0(); SCB();
        QMMA(1)
        BAR();

        RD_A(0, 2)
        if (!lst) { ST_B(0, 1, 128) }
        BAR(); LGK0(); SCB();
        QMMA(2)
        BAR();

        RD_A(0, 3)
        BAR(); LGK0(); SCB();
        QMMA(3)
        if (lst) { VMC(0); } else { VMC(4); }
        BAR();

        RD_A(16384, 0) RD_B(16384, 0) RD_B(16384, 1) RD_B(16384, 2) RD_B(16384, 3)
        if (!lst) { ST_A(0, 0, 128) }
        LGK8();
        BAR(); LGK0(); SCB();
        QMMA(0)
        BAR();

        RD_A(16384, 1)
        if (!lst) { ST_A(0, 1, 128) }
        BAR(); LGK0(); SCB();
        QMMA(1)
        BAR();

        RD_A(16384, 2)
        if (!lst) { ST_B(16384, 0, 192) }
        BAR(); LGK0(); SCB();
        QMMA(2)
        BAR();

        RD_A(16384, 3)
        if (!lst) { ST_B(16384, 1, 192) }
        BAR(); LGK0(); SCB();
        QMMA(3)
        if (!lst) { VMC(4); }
        BAR();

        pA0 += 128; pA1 += 128; pB0 += 128; pB1 += 128;
    }

#undef QMMA
#undef ST_B
#undef ST_A
#undef RD_B
#undef RD_A
}

// ---------------------------------------------------------------------------
// Merged QKV GEMM (unchanged): 256x256 tiles, 384 blocks.
// ---------------------------------------------------------------------------
__global__ __launch_bounds__(512, 2) void gemm_qkv_kernel(
    const bf16_t* __restrict__ X, const bf16_t* __restrict__ Wt,
    bf16_t* __restrict__ Qt, bf16_t* __restrict__ Kt, bf16_t* __restrict__ Vtr,
    const float2* __restrict__ rope)
{
    __shared__ __align__(16) bf16_t L[65536];   // 128 KiB

    const int tid = threadIdx.x;
    const int xcd = blockIdx.x & 7;
    const int idx = blockIdx.x >> 3;
    const int mt  = xcd * 4 + (idx & 3);
    const int nt  = idx >> 2;
    const int m0 = mt << 8, n0 = nt << 8;
    const bool tr = (n0 >= 2 * DM);

    f32x4 acc[8][4] = {};
    if (tr) kloop<true >(X + (size_t)m0 * DM, Wt + (size_t)n0 * DM, L, tid, acc);
    else    kloop<false>(X + (size_t)m0 * DM, Wt + (size_t)n0 * DM, L, tid, acc);

    const int lane = tid & 63;
    const int wave = tid >> 6;
    const int wm   = wave >> 2, wn = wave & 3;
    const int l    = lane & 15;
    const int quad = lane >> 4;

#pragma unroll
    for (int mf = 0; mf < 8; ++mf)
#pragma unroll
        for (int nf = 0; nf < 4; ++nf)
#pragma unroll
            for (int r = 0; r < 4; ++r) {
                float v = acc[mf][nf][r];
                if (tr) {
                    const int n = n0 + wn * 64 + nf * 16 + quad * 4 + r;
                    const int m = m0 + wm * 128 + mf * 16 + l;
                    const int bi = m >> 11, s = m & (SEQ - 1);
                    const int col = n & (DM - 1);
                    const int h = col >> 6, d = col & (DK - 1);
                    Vtr[(((size_t)(bi * NH + h)) * DK + d) * SEQ + s] = (bf16_t)v;
                } else {
                    const int m  = m0 + wm * 128 + mf * 16 + quad * 4 + r;
                    const int nn = n0 + wn * 64 + nf * 16 + l;
                    const int bi = m >> 11, s = m & (SEQ - 1);
                    const int col = nn & (DM - 1);
                    const int h = col >> 6, d = col & (DK - 1);
                    float pv = __shfl_xor(v, 1);
                    float2 cs = rope[s * 32 + (d >> 1)];
                    float res = (d & 1) ? (v * cs.x + pv * cs.y)
                                        : (v * cs.x - pv * cs.y);
                    bf16_t* dst = (nn < DM) ? Qt : Kt;
                    if (nn < DM) res *= 0.125f;   // fold 1/sqrt(dk) into Q
                    dst[(((size_t)(bi * NH + h)) * SEQ + s) * DK + d] = (bf16_t)res;
                }
            }
}

// ---------------------------------------------------------------------------
// Output projection GEMM (unchanged): 128m x 256n, 256 blocks = 1 round.
// ---------------------------------------------------------------------------
__global__ __launch_bounds__(512, 2) void gemm_out_kernel(
    const bf16_t* __restrict__ X, const bf16_t* __restrict__ Wt,
    float* __restrict__ out)
{
    __shared__ __align__(16) bf16_t L[49152];   // 96 KiB

    const int tid = threadIdx.x;
    const int xcd = blockIdx.x & 7;
    const int idx = blockIdx.x >> 3;               // 0..31
    const int mt  = xcd * 8 + (idx & 7);           // 0..63
    const int nt  = idx >> 3;                      // 0..3
    const int m0 = mt << 7, n0 = nt << 8;

    const int lane = tid & 63;
    const int wave = tid >> 6;
    const int wm   = wave >> 2;
    const int wn   = wave & 3;
    const int lrow = lane & 15;
    const int lcol = (lane >> 4) << 3;

    bf16_t* const AR = L;                    // 2 bufs x 8192 elems
    bf16_t* const BR = L + 16384;            // 2 bufs x 16384 elems

    const bf16_t* Xp = X + (size_t)m0 * DM;
    const bf16_t* Wp = Wt + (size_t)n0 * DM;
    const bf16_t* pA  = Xp + (size_t)(wave * 16 + lrow) * DM + lcol;
    const bf16_t* pB0 = Wp + (size_t)(wave * 16 + lrow) * DM + lcol;
    const bf16_t* pB1 = pB0 + (size_t)128 * DM;

    bf16_t* const adst = AR + wave * 1024;
    bf16_t* const bdst = BR + wave * 1024;

    const bf16_t* const Ard = AR + wm * 4096;
    const bf16_t* const Brd = BR + wn * 4096;

    f32x4 acc[4][4] = {};
    bf16x8 a[2][2], bc[4][2];

#define RD_AH(BUF, Q)                                                         \
    a[0][0] = *(const bf16x8*)(Ard + (BUF) + (2*(Q)+0)*1024 + lane*8);        \
    a[0][1] = *(const bf16x8*)(Ard + (BUF) + (2*(Q)+0)*1024 + 512 + lane*8);  \
    a[1][0] = *(const bf16x8*)(Ard + (BUF) + (2*(Q)+1)*1024 + lane*8);        \
    a[1][1] = *(const bf16x8*)(Ard + (BUF) + (2*(Q)+1)*1024 + 512 + lane*8);

#define RD_BH(BUF, NF)                                                        \
    bc[NF][0] = *(const bf16x8*)(Brd + (BUF) + (NF)*1024 + lane*8);           \
    bc[NF][1] = *(const bf16x8*)(Brd + (BUF) + (NF)*1024 + 512 + lane*8);

#define ST_AH(BUF, C)                                                         \
    gl2lds16(pA + (C),      adst + (BUF));                                    \
    gl2lds16(pA + (C) + 32, adst + (BUF) + 512);

#define ST_BH(BUF, H, C)                                                      \
    gl2lds16(((H) ? pB1 : pB0) + (C),      bdst + (BUF) + (H)*8192);          \
    gl2lds16(((H) ? pB1 : pB0) + (C) + 32, bdst + (BUF) + (H)*8192 + 512);

#define QMMAH(Q)                                                              \
    __builtin_amdgcn_s_setprio(1);                                            \
    _Pragma("unroll")                                                         \
    for (int nf = 0; nf < 4; ++nf) {                                          \
        acc[2*(Q)][nf]   = MFMA16(a[0][0], bc[nf][0], acc[2*(Q)][nf]);        \
        acc[2*(Q)][nf]   = MFMA16(a[0][1], bc[nf][1], acc[2*(Q)][nf]);        \
        acc[2*(Q)+1][nf] = MFMA16(a[1][0], bc[nf][0], acc[2*(Q)+1][nf]);      \
        acc[2*(Q)+1][nf] = MFMA16(a[1][1], bc[nf][1], acc[2*(Q)+1][nf]);      \
    }                                                                         \
    __builtin_amdgcn_s_setprio(0);

    ST_AH(0, 0)
    ST_BH(0, 0, 0) ST_BH(0, 1, 0)
    ST_BH(16384, 0, 64) ST_BH(16384, 1, 64)
    VMC(4);
    BAR();

    for (int it = 0; it < 8; ++it) {
        const bool lst = (it == 7);

        RD_AH(0, 0) RD_BH(0, 0) RD_BH(0, 1) RD_BH(0, 2) RD_BH(0, 3)
        ST_AH(8192, 64)
        LGK8();
        BAR(); LGK0(); SCB();
        QMMAH(0)
        BAR();
        RD_AH(0, 1)
        if (!lst) { ST_BH(0, 0, 128) ST_BH(0, 1, 128) }
        BAR(); LGK0(); SCB();
        QMMAH(1)
        if (lst) { VMC(0); } else { VMC(4); }
        BAR();

        RD_AH(8192, 0) RD_BH(16384, 0) RD_BH(16384, 1) RD_BH(16384, 2) RD_BH(16384, 3)
        if (!lst) { ST_AH(0, 128) }
        LGK8();
        BAR(); LGK0(); SCB();
        QMMAH(0)
        BAR();
        RD_AH(8192, 1)
        if (!lst) { ST_BH(16384, 0, 192) ST_BH(16384, 1, 192) }
        BAR(); LGK0(); SCB();
        QMMAH(1)
        if (!lst) { VMC(4); }
        BAR();

        pA += 128; pB0 += 128; pB1 += 128;
    }

#undef QMMAH
#undef ST_BH
#undef ST_AH
#undef RD_BH
#undef RD_AH

    const int l    = lane & 15;
    const int quad = lane >> 4;
#pragma unroll
    for (int mf = 0; mf < 4; ++mf)
#pragma unroll
        for (int nf = 0; nf < 4; ++nf)
#pragma unroll
            for (int r = 0; r < 4; ++r) {
                const int m  = m0 + wm * 64 + mf * 16 + quad * 4 + r;
                const int nn = n0 + wn * 64 + nf * 16 + l;
                out[(size_t)m * DM + nn] = acc[mf][nf][r];
            }
}

// ---------------------------------------------------------------------------
// Causal flash attention v2 — BARRIER-FREE.
// K/V per head = 512KB; per-XCD 8 heads = 4MB = L2-resident (grid bid%8 =
// bh%8).  So read K and V fragments DIRECTLY from global (L2) instead of
// LDS-staging them: per wave, fragment loads are 16 rows x 64B contiguous
// (100% cache-line utilization).  This deletes all __syncthreads -- P-tiles
// are per-wave, so the 4 waves run fully independently with per-wave causal
// chunk bounds (no dead iterations).  V-frags issued right after QK^T so
// their L2 latency hides under the softmax VALU chain.  LDS: only P staging
// (18KB).  setprio around MFMA clusters (m191: helps attn's indep waves).
// ---------------------------------------------------------------------------
#define KLD 72   // P LDS row stride (elems): 144 B

__global__ __launch_bounds__(256) void attn_kernel(
    const bf16_t* __restrict__ Q, const bf16_t* __restrict__ K,
    const bf16_t* __restrict__ Vt, bf16_t* __restrict__ O)
{
    __shared__ __align__(16) bf16_t Pl[4][32 * KLD];

    const int bh   = blockIdx.x;          // bh fast dim -> bid%8 = bh%8
    const int qx   = blockIdx.y;          // q-chunk index 0..7
    const int tid  = threadIdx.x;
    const int wave = tid >> 6;
    const int lane = tid & 63;
    const int l    = lane & 15;
    const int quad = lane >> 4;

    bf16_t* Pw = Pl[wave];
    const bf16_t* Qb = Q  + (size_t)bh * SEQ * DK;
    const bf16_t* Kb = K  + (size_t)bh * SEQ * DK;
    const bf16_t* Vb = Vt + (size_t)bh * DK * SEQ;
    const int b = bh >> 4, h = bh & 15;

    for (int ph = 0; ph < 2; ++ph) {
        const int qblk = ph ? (15 - qx) : qx;
        const int q0w  = qblk * 128 + wave * 32;
        // last chunk needed: rows <= q0w+31  ->  per-wave count:
        const int nchw = 2 * qblk + 1 + (wave >> 1);

        bf16x8 qb[2][2];
#pragma unroll
        for (int u = 0; u < 2; ++u) {
            qb[u][0] = *(const bf16x8*)(Qb + (size_t)(q0w + u * 16 + l) * DK + quad * 8);
            qb[u][1] = *(const bf16x8*)(Qb + (size_t)(q0w + u * 16 + l) * DK + 32 + quad * 8);
        }

        float m_run[2] = {-3e38f, -3e38f};
        float l_run[2] = {0.f, 0.f};
        f32x4 o[4][2] = {};

        for (int i = 0; i < nchw; ++i) {
            const int c = i * 64;

            // ---- QK^T: K-frags direct from L2 ----
            f32x4 st[4][2] = {};
            __builtin_amdgcn_s_setprio(1);
#pragma unroll
            for (int t = 0; t < 4; ++t) {
                const bf16x8 k0 = *(const bf16x8*)(Kb + (size_t)(c + t * 16 + l) * DK + quad * 8);
                const bf16x8 k1 = *(const bf16x8*)(Kb + (size_t)(c + t * 16 + l) * DK + 32 + quad * 8);
                st[t][0] = MFMA16(k0, qb[0][0], st[t][0]);
                st[t][0] = MFMA16(k1, qb[0][1], st[t][0]);
                st[t][1] = MFMA16(k0, qb[1][0], st[t][1]);
                st[t][1] = MFMA16(k1, qb[1][1], st[t][1]);
            }
            __builtin_amdgcn_s_setprio(0);

            // ---- V-frag prefetch: latency hides under softmax ----
            bf16x8 vf[4][2];
#pragma unroll
            for (int n = 0; n < 4; ++n) {
                vf[n][0] = *(const bf16x8*)(Vb + (size_t)(n * 16 + l) * SEQ + c + quad * 8);
                vf[n][1] = *(const bf16x8*)(Vb + (size_t)(n * 16 + l) * SEQ + c + 32 + quad * 8);
            }

            // ---- causal mask ----
            if (c + 63 > q0w) {
#pragma unroll
                for (int u = 0; u < 2; ++u) {
                    const int thr = q0w + u * 16 + l - c - quad * 4;
#pragma unroll
                    for (int t = 0; t < 4; ++t)
#pragma unroll
                        for (int r = 0; r < 4; ++r)
                            if (t * 16 + r > thr) st[t][u][r] = -3e38f;
                }
            }

            // ---- online softmax ----
#pragma unroll
            for (int u = 0; u < 2; ++u) {
                float cmax = -3e38f;
#pragma unroll
                for (int t = 0; t < 4; ++t)
#pragma unroll
                    for (int r = 0; r < 4; ++r)
                        cmax = fmaxf(cmax, st[t][u][r]);
                cmax = fmaxf(cmax, __shfl_xor(cmax, 16));
                cmax = fmaxf(cmax, __shfl_xor(cmax, 32));
                const float mnew  = fmaxf(m_run[u], cmax);
                const float alpha = __expf(m_run[u] - mnew);
                m_run[u] = mnew;
                float csum = 0.f;
#pragma unroll
                for (int t = 0; t < 4; ++t)
#pragma unroll
                    for (int r = 0; r < 4; ++r) {
                        st[t][u][r] = __expf(st[t][u][r] - mnew);
                        csum += st[t][u][r];
                    }
                csum += __shfl_xor(csum, 16);
                csum += __shfl_xor(csum, 32);
                l_run[u] = l_run[u] * alpha + csum;
#pragma unroll
                for (int n = 0; n < 4; ++n)
#pragma unroll
                    for (int r = 0; r < 4; ++r)
                        o[n][u][r] *= alpha;
#pragma unroll
                for (int t = 0; t < 4; ++t) {
                    bf16x4 pk;
                    pk[0] = (bf16_t)st[t][u][0]; pk[1] = (bf16_t)st[t][u][1];
                    pk[2] = (bf16_t)st[t][u][2]; pk[3] = (bf16_t)st[t][u][3];
                    *(bf16x4*)(Pw + (u * 16 + l) * KLD + t * 16 + quad * 4) = pk;
                }
            }

            // ---- PV: P via per-wave LDS transpose, V from prefetched regs ----
            const bf16x8 pb00 = *(const bf16x8*)(Pw + l * KLD + quad * 8);
            const bf16x8 pb01 = *(const bf16x8*)(Pw + l * KLD + 32 + quad * 8);
            const bf16x8 pb10 = *(const bf16x8*)(Pw + (16 + l) * KLD + quad * 8);
            const bf16x8 pb11 = *(const bf16x8*)(Pw + (16 + l) * KLD + 32 + quad * 8);
            __builtin_amdgcn_s_setprio(1);
#pragma unroll
            for (int n = 0; n < 4; ++n) {
                o[n][0] = MFMA16(vf[n][0], pb00, o[n][0]);
                o[n][0] = MFMA16(vf[n][1], pb01, o[n][0]);
                o[n][1] = MFMA16(vf[n][0], pb10, o[n][1]);
                o[n][1] = MFMA16(vf[n][1], pb11, o[n][1]);
            }
            __builtin_amdgcn_s_setprio(0);
        }

        // ---- epilogue (per-wave, unchanged) ----
#pragma unroll
        for (int u = 0; u < 2; ++u) {
            const float inv = 1.0f / l_run[u];
#pragma unroll
            for (int n = 0; n < 4; ++n) {
                bf16x4 ov;
                ov[0] = (bf16_t)(o[n][u][0] * inv); ov[1] = (bf16_t)(o[n][u][1] * inv);
                ov[2] = (bf16_t)(o[n][u][2] * inv); ov[3] = (bf16_t)(o[n][u][3] * inv);
                *(bf16x4*)(Pw + (u * 16 + l) * KLD + n * 16 + quad * 4) = ov;
            }
        }
        const int row  = lane >> 1;
        const int half = (lane & 1) * 32;
        const bf16x8 w0 = *(const bf16x8*)(Pw + row * KLD + half);
        const bf16x8 w1 = *(const bf16x8*)(Pw + row * KLD + half + 8);
        const bf16x8 w2 = *(const bf16x8*)(Pw + row * KLD + half + 16);
        const bf16x8 w3 = *(const bf16x8*)(Pw + row * KLD + half + 24);
        bf16_t* op = O + ((size_t)(b * SEQ + qblk * 128 + wave * 32 + row)) * DM
                       + h * DK + half;
        *(bf16x8*)(op)      = w0;
        *(bf16x8*)(op + 8)  = w1;
        *(bf16x8*)(op + 16) = w2;
        *(bf16x8*)(op + 24) = w3;
    }
}

// ---------------------------------------------------------------------------
extern "C" void kernel_launch(void* const* d_in, const int* in_sizes, int n_in,
                              void* d_out, int out_size, void* d_ws, size_t ws_size,
                              hipStream_t stream)
{
    const float* x  = (const float*)d_in[0];
    const float* Wq = (const float*)d_in[1];
    const float* Wk = (const float*)d_in[2];
    const float* Wv = (const float*)d_in[3];
    const float* Wo = (const float*)d_in[4];

    char* ws = (char*)d_ws;
    float2* rope = (float2*)ws;                        // 512 KiB
    const size_t TEN = (size_t)MROWS * DM;
    bf16_t* xb    = (bf16_t*)(ws + (1 << 19));
    bf16_t* Wqkvt = xb + TEN;                          // [3072][1024] concat
    bf16_t* Wot   = Wqkvt + 3 * (size_t)WEL;
    bf16_t* Qt    = Wot + WEL;
    bf16_t* Kt    = Qt + TEN;
    bf16_t* Vt    = Kt + TEN;
    bf16_t* Ot    = Vt + TEN;

    // fused preprocessing: cvt + 4x wtr + rope in one launch
    prep_kernel<<<12544, 256, 0, stream>>>(x, Wq, Wk, Wv, Wo,
                                           xb, Wqkvt, Wot, rope);

    // merged QKV: 32 mt x 12 nt of 256^2, 8-phase schedule
    gemm_qkv_kernel<<<32 * 12, 512, 0, stream>>>(xb, Wqkvt, Qt, Kt, Vt, rope);

    // grid (bh, qchunk): bid%8 = bh%8 -> per-XCD K/V locality
    attn_kernel<<<dim3(NB * NH, 8), 256, 0, stream>>>(Qt, Kt, Vt, Ot);

    // out: 64 mt x 4 nt of 128x256 = 256 blocks = one exact round
    gemm_out_kernel<<<64 * 4, 512, 0, stream>>>(Ot, Wot, (float*)d_out);
}

// Round 9
// 294.281 us; speedup vs baseline: 1.1723x; 1.1723x over previous
//
#include <hip/hip_runtime.h>
#include <hip/hip_bf16.h>

// Problem constants: B=4, S=2048, D=1024, H=16, dk=64
#define SEQ   2048
#define NB    4
#define NH    16
#define DK    64
#define DM    1024
#define MROWS (NB * SEQ)   // 8192
#define WEL   (DM * DM)

typedef __bf16 bf16_t;
typedef __bf16 bf16x8 __attribute__((ext_vector_type(8)));
typedef __bf16 bf16x4 __attribute__((ext_vector_type(4)));
typedef float  f32x4  __attribute__((ext_vector_type(4)));

#define MFMA16(a, b, c) __builtin_amdgcn_mfma_f32_16x16x32_bf16((a), (b), (c), 0, 0, 0)

// async global->LDS, 16B per lane; LDS dest wave-uniform, HW scatters +lane*16
__device__ __forceinline__ void gl2lds16(const bf16_t* g, bf16_t* l) {
    __builtin_amdgcn_global_load_lds(
        (const __attribute__((address_space(1))) unsigned int*)g,
        (__attribute__((address_space(3))) unsigned int*)l, 16, 0, 0);
}

#define BAR()   __builtin_amdgcn_s_barrier()
#define SCB()   __builtin_amdgcn_sched_barrier(0)
#define LGK0()  asm volatile("s_waitcnt lgkmcnt(0)")
#define LGK8()  asm volatile("s_waitcnt lgkmcnt(8)")
#define VMC(N)  asm volatile("s_waitcnt vmcnt(" #N ")")

// ---------------------------------------------------------------------------
// Fused preprocessing: cvt (blocks 0..8191) + 4x weight transpose
// (8192..12287) + rope table (12288..12543).  One launch instead of six.
// ---------------------------------------------------------------------------
__global__ __launch_bounds__(256) void prep_kernel(
    const float* __restrict__ x,
    const float* __restrict__ Wq, const float* __restrict__ Wk,
    const float* __restrict__ Wv, const float* __restrict__ Wo,
    bf16_t* __restrict__ xb, bf16_t* __restrict__ Wqkvt,
    bf16_t* __restrict__ Wot, float2* __restrict__ rope)
{
    __shared__ float T[32][33];
    const int bid = blockIdx.x;
    const int tid = threadIdx.x;

    if (bid < 8192) {                       // fp32 -> bf16 conversion of x
        const int i = (bid * 256 + tid) * 4;
        const float4 v = *(const float4*)(x + i);
        bf16x4 o;
        o[0] = (bf16_t)v.x; o[1] = (bf16_t)v.y;
        o[2] = (bf16_t)v.z; o[3] = (bf16_t)v.w;
        *(bf16x4*)(xb + i) = o;
    } else if (bid < 12288) {               // weight transpose + cast
        const int wb = bid - 8192;
        const int w  = wb >> 10;            // which matrix
        const int b10 = wb & 1023;
        const float* W = (w == 0) ? Wq : (w == 1) ? Wk : (w == 2) ? Wv : Wo;
        bf16_t* Wt = (w == 3) ? Wot : Wqkvt + (size_t)w * WEL;
        const int tk0 = (b10 >> 5) << 5;
        const int tn0 = (b10 & 31) << 5;
        const int r = tid >> 5, c = tid & 31;
#pragma unroll
        for (int i = 0; i < 4; ++i)
            T[r + i * 8][c] = W[(size_t)(tk0 + r + i * 8) * DM + tn0 + c];
        __syncthreads();
#pragma unroll
        for (int i = 0; i < 4; ++i)
            Wt[(size_t)(tn0 + r + i * 8) * DM + tk0 + c] = (bf16_t)T[c][r + i * 8];
    } else {                                // rope table
        const int idx = (bid - 12288) * 256 + tid;
        const int s = idx >> 5, i = idx & 31;
        const float freq = powf(10000.0f, -(float)i / 32.0f);
        const float a = (float)s * freq;
        rope[idx] = make_float2(cosf(a), sinf(a));
    }
}

// ---------------------------------------------------------------------------
// 256x256xBK64 8-phase K-loop (unchanged — QKV structure plateau).
// ---------------------------------------------------------------------------
template<bool TR>
__device__ __forceinline__ void kloop(
    const bf16_t* __restrict__ Xp, const bf16_t* __restrict__ Wp,
    bf16_t* L, int tid, f32x4 (&acc)[8][4])
{
    const int lane = tid & 63;
    const int wave = tid >> 6;
    const int wm   = wave >> 2;
    const int wn   = wave & 3;
    const int lrow = lane & 15;
    const int lcol = (lane >> 4) << 3;

    bf16_t* const AR = L;
    bf16_t* const BR = L + 32768;

    const bf16_t* pA0 = Xp + (size_t)(wave * 16 + lrow) * DM + lcol;
    const bf16_t* pA1 = pA0 + (size_t)128 * DM;
    const bf16_t* pB0 = Wp + (size_t)(wave * 16 + lrow) * DM + lcol;
    const bf16_t* pB1 = pB0 + (size_t)128 * DM;

    bf16_t* const adst = AR + wave * 1024;
    bf16_t* const bdst = BR + wave * 1024;

    const bf16_t* const Ard = AR + wm * 8192;
    const bf16_t* const Brd = BR + wn * 4096;

    bf16x8 a[2][2], bc[4][2];

#define RD_A(BUF, Q)                                                          \
    a[0][0] = *(const bf16x8*)(Ard + (BUF) + (2*(Q)+0)*1024 + lane*8);        \
    a[0][1] = *(const bf16x8*)(Ard + (BUF) + (2*(Q)+0)*1024 + 512 + lane*8);  \
    a[1][0] = *(const bf16x8*)(Ard + (BUF) + (2*(Q)+1)*1024 + lane*8);        \
    a[1][1] = *(const bf16x8*)(Ard + (BUF) + (2*(Q)+1)*1024 + 512 + lane*8);

#define RD_B(BUF, NF)                                                         \
    bc[NF][0] = *(const bf16x8*)(Brd + (BUF) + (NF)*1024 + lane*8);           \
    bc[NF][1] = *(const bf16x8*)(Brd + (BUF) + (NF)*1024 + 512 + lane*8);

#define ST_A(BUF, H, C)                                                       \
    gl2lds16(((H) ? pA1 : pA0) + (C),      adst + (BUF) + (H)*8192);          \
    gl2lds16(((H) ? pA1 : pA0) + (C) + 32, adst + (BUF) + (H)*8192 + 512);

#define ST_B(BUF, H, C)                                                       \
    gl2lds16(((H) ? pB1 : pB0) + (C),      bdst + (BUF) + (H)*8192);          \
    gl2lds16(((H) ? pB1 : pB0) + (C) + 32, bdst + (BUF) + (H)*8192 + 512);

#define QMMA(Q)                                                               \
    __builtin_amdgcn_s_setprio(1);                                            \
    _Pragma("unroll")                                                         \
    for (int nf = 0; nf < 4; ++nf) {                                          \
        if (TR) {                                                             \
            acc[2*(Q)][nf]   = MFMA16(bc[nf][0], a[0][0], acc[2*(Q)][nf]);    \
            acc[2*(Q)][nf]   = MFMA16(bc[nf][1], a[0][1], acc[2*(Q)][nf]);    \
            acc[2*(Q)+1][nf] = MFMA16(bc[nf][0], a[1][0], acc[2*(Q)+1][nf]);  \
            acc[2*(Q)+1][nf] = MFMA16(bc[nf][1], a[1][1], acc[2*(Q)+1][nf]);  \
        } else {                                                              \
            acc[2*(Q)][nf]   = MFMA16(a[0][0], bc[nf][0], acc[2*(Q)][nf]);    \
            acc[2*(Q)][nf]   = MFMA16(a[0][1], bc[nf][1], acc[2*(Q)][nf]);    \
            acc[2*(Q)+1][nf] = MFMA16(a[1][0], bc[nf][0], acc[2*(Q)+1][nf]);  \
            acc[2*(Q)+1][nf] = MFMA16(a[1][1], bc[nf][1], acc[2*(Q)+1][nf]);  \
        }                                                                     \
    }                                                                         \
    __builtin_amdgcn_s_setprio(0);

    ST_B(0, 0, 0)      ST_B(0, 1, 0)
    ST_A(0, 0, 0)      ST_A(0, 1, 0)
    ST_B(16384, 0, 64) ST_B(16384, 1, 64)
    VMC(4);
    BAR();

    for (int it = 0; it < 8; ++it) {
        const bool lst = (it == 7);

        RD_A(0, 0) RD_B(0, 0) RD_B(0, 1) RD_B(0, 2) RD_B(0, 3)
        ST_A(16384, 0, 64) ST_A(16384, 1, 64)
        LGK8();
        BAR(); LGK0(); SCB();
        QMMA(0)
        BAR();

        RD_A(0, 1)
        if (!lst) { ST_B(0, 0, 128) }
        BAR(); LGK0(); SCB();
        QMMA(1)
        BAR();

        RD_A(0, 2)
        if (!lst) { ST_B(0, 1, 128) }
        BAR(); LGK0(); SCB();
        QMMA(2)
        BAR();

        RD_A(0, 3)
        BAR(); LGK0(); SCB();
        QMMA(3)
        if (lst) { VMC(0); } else { VMC(4); }
        BAR();

        RD_A(16384, 0) RD_B(16384, 0) RD_B(16384, 1) RD_B(16384, 2) RD_B(16384, 3)
        if (!lst) { ST_A(0, 0, 128) }
        LGK8();
        BAR(); LGK0(); SCB();
        QMMA(0)
        BAR();

        RD_A(16384, 1)
        if (!lst) { ST_A(0, 1, 128) }
        BAR(); LGK0(); SCB();
        QMMA(1)
        BAR();

        RD_A(16384, 2)
        if (!lst) { ST_B(16384, 0, 192) }
        BAR(); LGK0(); SCB();
        QMMA(2)
        BAR();

        RD_A(16384, 3)
        if (!lst) { ST_B(16384, 1, 192) }
        BAR(); LGK0(); SCB();
        QMMA(3)
        if (!lst) { VMC(4); }
        BAR();

        pA0 += 128; pA1 += 128; pB0 += 128; pB1 += 128;
    }

#undef QMMA
#undef ST_B
#undef ST_A
#undef RD_B
#undef RD_A
}

// ---------------------------------------------------------------------------
// Merged QKV GEMM (unchanged): 256x256 tiles, 384 blocks.
// ---------------------------------------------------------------------------
__global__ __launch_bounds__(512, 2) void gemm_qkv_kernel(
    const bf16_t* __restrict__ X, const bf16_t* __restrict__ Wt,
    bf16_t* __restrict__ Qt, bf16_t* __restrict__ Kt, bf16_t* __restrict__ Vtr,
    const float2* __restrict__ rope)
{
    __shared__ __align__(16) bf16_t L[65536];   // 128 KiB

    const int tid = threadIdx.x;
    const int xcd = blockIdx.x & 7;
    const int idx = blockIdx.x >> 3;
    const int mt  = xcd * 4 + (idx & 3);
    const int nt  = idx >> 2;
    const int m0 = mt << 8, n0 = nt << 8;
    const bool tr = (n0 >= 2 * DM);

    f32x4 acc[8][4] = {};
    if (tr) kloop<true >(X + (size_t)m0 * DM, Wt + (size_t)n0 * DM, L, tid, acc);
    else    kloop<false>(X + (size_t)m0 * DM, Wt + (size_t)n0 * DM, L, tid, acc);

    const int lane = tid & 63;
    const int wave = tid >> 6;
    const int wm   = wave >> 2, wn = wave & 3;
    const int l    = lane & 15;
    const int quad = lane >> 4;

#pragma unroll
    for (int mf = 0; mf < 8; ++mf)
#pragma unroll
        for (int nf = 0; nf < 4; ++nf)
#pragma unroll
            for (int r = 0; r < 4; ++r) {
                float v = acc[mf][nf][r];
                if (tr) {
                    const int n = n0 + wn * 64 + nf * 16 + quad * 4 + r;
                    const int m = m0 + wm * 128 + mf * 16 + l;
                    const int bi = m >> 11, s = m & (SEQ - 1);
                    const int col = n & (DM - 1);
                    const int h = col >> 6, d = col & (DK - 1);
                    Vtr[(((size_t)(bi * NH + h)) * DK + d) * SEQ + s] = (bf16_t)v;
                } else {
                    const int m  = m0 + wm * 128 + mf * 16 + quad * 4 + r;
                    const int nn = n0 + wn * 64 + nf * 16 + l;
                    const int bi = m >> 11, s = m & (SEQ - 1);
                    const int col = nn & (DM - 1);
                    const int h = col >> 6, d = col & (DK - 1);
                    float pv = __shfl_xor(v, 1);
                    float2 cs = rope[s * 32 + (d >> 1)];
                    float res = (d & 1) ? (v * cs.x + pv * cs.y)
                                        : (v * cs.x - pv * cs.y);
                    bf16_t* dst = (nn < DM) ? Qt : Kt;
                    if (nn < DM) res *= 0.125f;   // fold 1/sqrt(dk) into Q
                    dst[(((size_t)(bi * NH + h)) * SEQ + s) * DK + d] = (bf16_t)res;
                }
            }
}

// ---------------------------------------------------------------------------
// Output projection GEMM (unchanged): 128m x 256n, 256 blocks = 1 round.
// ---------------------------------------------------------------------------
__global__ __launch_bounds__(512, 2) void gemm_out_kernel(
    const bf16_t* __restrict__ X, const bf16_t* __restrict__ Wt,
    float* __restrict__ out)
{
    __shared__ __align__(16) bf16_t L[49152];   // 96 KiB

    const int tid = threadIdx.x;
    const int xcd = blockIdx.x & 7;
    const int idx = blockIdx.x >> 3;               // 0..31
    const int mt  = xcd * 8 + (idx & 7);           // 0..63
    const int nt  = idx >> 3;                      // 0..3
    const int m0 = mt << 7, n0 = nt << 8;

    const int lane = tid & 63;
    const int wave = tid >> 6;
    const int wm   = wave >> 2;
    const int wn   = wave & 3;
    const int lrow = lane & 15;
    const int lcol = (lane >> 4) << 3;

    bf16_t* const AR = L;                    // 2 bufs x 8192 elems
    bf16_t* const BR = L + 16384;            // 2 bufs x 16384 elems

    const bf16_t* Xp = X + (size_t)m0 * DM;
    const bf16_t* Wp = Wt + (size_t)n0 * DM;
    const bf16_t* pA  = Xp + (size_t)(wave * 16 + lrow) * DM + lcol;
    const bf16_t* pB0 = Wp + (size_t)(wave * 16 + lrow) * DM + lcol;
    const bf16_t* pB1 = pB0 + (size_t)128 * DM;

    bf16_t* const adst = AR + wave * 1024;
    bf16_t* const bdst = BR + wave * 1024;

    const bf16_t* const Ard = AR + wm * 4096;
    const bf16_t* const Brd = BR + wn * 4096;

    f32x4 acc[4][4] = {};
    bf16x8 a[2][2], bc[4][2];

#define RD_AH(BUF, Q)                                                         \
    a[0][0] = *(const bf16x8*)(Ard + (BUF) + (2*(Q)+0)*1024 + lane*8);        \
    a[0][1] = *(const bf16x8*)(Ard + (BUF) + (2*(Q)+0)*1024 + 512 + lane*8);  \
    a[1][0] = *(const bf16x8*)(Ard + (BUF) + (2*(Q)+1)*1024 + lane*8);        \
    a[1][1] = *(const bf16x8*)(Ard + (BUF) + (2*(Q)+1)*1024 + 512 + lane*8);

#define RD_BH(BUF, NF)                                                        \
    bc[NF][0] = *(const bf16x8*)(Brd + (BUF) + (NF)*1024 + lane*8);           \
    bc[NF][1] = *(const bf16x8*)(Brd + (BUF) + (NF)*1024 + 512 + lane*8);

#define ST_AH(BUF, C)                                                         \
    gl2lds16(pA + (C),      adst + (BUF));                                    \
    gl2lds16(pA + (C) + 32, adst + (BUF) + 512);

#define ST_BH(BUF, H, C)                                                      \
    gl2lds16(((H) ? pB1 : pB0) + (C),      bdst + (BUF) + (H)*8192);          \
    gl2lds16(((H) ? pB1 : pB0) + (C) + 32, bdst + (BUF) + (H)*8192 + 512);

#define QMMAH(Q)                                                              \
    __builtin_amdgcn_s_setprio(1);                                            \
    _Pragma("unroll")                                                         \
    for (int nf = 0; nf < 4; ++nf) {                                          \
        acc[2*(Q)][nf]   = MFMA16(a[0][0], bc[nf][0], acc[2*(Q)][nf]);        \
        acc[2*(Q)][nf]   = MFMA16(a[0][1], bc[nf][1], acc[2*(Q)][nf]);        \
        acc[2*(Q)+1][nf] = MFMA16(a[1][0], bc[nf][0], acc[2*(Q)+1][nf]);      \
        acc[2*(Q)+1][nf] = MFMA16(a[1][1], bc[nf][1], acc[2*(Q)+1][nf]);      \
    }                                                                         \
    __builtin_amdgcn_s_setprio(0);

    ST_AH(0, 0)
    ST_BH(0, 0, 0) ST_BH(0, 1, 0)
    ST_BH(16384, 0, 64) ST_BH(16384, 1, 64)
    VMC(4);
    BAR();

    for (int it = 0; it < 8; ++it) {
        const bool lst = (it == 7);

        RD_AH(0, 0) RD_BH(0, 0) RD_BH(0, 1) RD_BH(0, 2) RD_BH(0, 3)
        ST_AH(8192, 64)
        LGK8();
        BAR(); LGK0(); SCB();
        QMMAH(0)
        BAR();
        RD_AH(0, 1)
        if (!lst) { ST_BH(0, 0, 128) ST_BH(0, 1, 128) }
        BAR(); LGK0(); SCB();
        QMMAH(1)
        if (lst) { VMC(0); } else { VMC(4); }
        BAR();

        RD_AH(8192, 0) RD_BH(16384, 0) RD_BH(16384, 1) RD_BH(16384, 2) RD_BH(16384, 3)
        if (!lst) { ST_AH(0, 128) }
        LGK8();
        BAR(); LGK0(); SCB();
        QMMAH(0)
        BAR();
        RD_AH(8192, 1)
        if (!lst) { ST_BH(16384, 0, 192) ST_BH(16384, 1, 192) }
        BAR(); LGK0(); SCB();
        QMMAH(1)
        if (!lst) { VMC(4); }
        BAR();

        pA += 128; pB0 += 128; pB1 += 128;
    }

#undef QMMAH
#undef ST_BH
#undef ST_AH
#undef RD_BH
#undef RD_AH

    const int l    = lane & 15;
    const int quad = lane >> 4;
#pragma unroll
    for (int mf = 0; mf < 4; ++mf)
#pragma unroll
        for (int nf = 0; nf < 4; ++nf)
#pragma unroll
            for (int r = 0; r < 4; ++r) {
                const int m  = m0 + wm * 64 + mf * 16 + quad * 4 + r;
                const int nn = n0 + wn * 64 + nf * 16 + l;
                out[(size_t)m * DM + nn] = acc[mf][nf][r];
            }
}

// ---------------------------------------------------------------------------
// Causal flash attention — REVERTED to the staged double-buffered form
// (R8's direct-L2 variant was latency-bound: MfmaUtil 10%, 137us).
// K/V double-buffer: load next chunk to regs at loop top (latency hides
// under compute), compute from buf b, write regs to buf b^1, one barrier.
// Additions this round: defer-max rescale skip (T13, +5% measured) and
// setprio around MFMA clusters (T5, +4-7% measured on attn).
// Grid (bh, qchunk): bid%8 = bh%8 -> per-XCD K/V locality.
// ---------------------------------------------------------------------------
#define KLD  72          // LDS row stride (elems): 144 B
#define KVSZ (64 * KLD)  // one K or V buffer

__global__ __launch_bounds__(256) void attn_kernel(
    const bf16_t* __restrict__ Q, const bf16_t* __restrict__ K,
    const bf16_t* __restrict__ Vt, bf16_t* __restrict__ O)
{
    __shared__ __align__(16) bf16_t Kl[2 * KVSZ];
    __shared__ __align__(16) bf16_t Vl[2 * KVSZ];
    __shared__ __align__(16) bf16_t Pl[4][32 * KLD];

    const int bh   = blockIdx.x;
    const int qx   = blockIdx.y;
    const int tid  = threadIdx.x;
    const int wave = tid >> 6;
    const int lane = tid & 63;
    const int l    = lane & 15;
    const int quad = lane >> 4;
    const int srow = tid >> 3;
    const int sch  = (tid & 7) << 3;

    bf16_t* Pw = Pl[wave];
    const bf16_t* Qb = Q  + (size_t)bh * SEQ * DK;
    const bf16_t* Kb = K  + (size_t)bh * SEQ * DK;
    const bf16_t* Vb = Vt + (size_t)bh * DK * SEQ;
    const int b = bh >> 4, h = bh & 15;

    for (int ph = 0; ph < 2; ++ph) {
        const int qblk = ph ? (15 - qx) : qx;
        const int q0w  = qblk * 128 + wave * 32;
        const int nch  = 2 * (qblk + 1);

        bf16x8 qb[2][2];
#pragma unroll
        for (int u = 0; u < 2; ++u) {
            qb[u][0] = *(const bf16x8*)(Qb + (size_t)(q0w + u * 16 + l) * DK + quad * 8);
            qb[u][1] = *(const bf16x8*)(Qb + (size_t)(q0w + u * 16 + l) * DK + 32 + quad * 8);
        }

        float m_run[2] = {-3e38f, -3e38f};
        float l_run[2] = {0.f, 0.f};
        f32x4 o[4][2] = {};

        // chunk 0 -> regs -> buf0
        bf16x8 pk0 = *(const bf16x8*)(Kb + (size_t)srow * DK + sch);
        bf16x8 pk1 = *(const bf16x8*)(Kb + (size_t)(32 + srow) * DK + sch);
        bf16x8 pv0 = *(const bf16x8*)(Vb + (size_t)srow * SEQ + sch);
        bf16x8 pv1 = *(const bf16x8*)(Vb + (size_t)(32 + srow) * SEQ + sch);
        __syncthreads();   // prev ph readers done before overwrite
        *(bf16x8*)(Kl + srow * KLD + sch)        = pk0;
        *(bf16x8*)(Kl + (32 + srow) * KLD + sch) = pk1;
        *(bf16x8*)(Vl + srow * KLD + sch)        = pv0;
        *(bf16x8*)(Vl + (32 + srow) * KLD + sch) = pv1;
        __syncthreads();

        for (int i = 0; i < nch; ++i) {
            const int c  = i * 64;
            const int bf = (i & 1) * KVSZ;       // current buffer
            const int bn = ((i & 1) ^ 1) * KVSZ; // next buffer
            const bool pf = (i + 1 < nch);

            if (pf) {   // issue next chunk's global loads (latency hides under compute)
                const int cn = c + 64;
                pk0 = *(const bf16x8*)(Kb + (size_t)(cn + srow) * DK + sch);
                pk1 = *(const bf16x8*)(Kb + (size_t)(cn + 32 + srow) * DK + sch);
                pv0 = *(const bf16x8*)(Vb + (size_t)srow * SEQ + cn + sch);
                pv1 = *(const bf16x8*)(Vb + (size_t)(32 + srow) * SEQ + cn + sch);
            }

            if (c <= q0w + 31) {
                const bf16_t* Klb = Kl + bf;
                const bf16_t* Vlb = Vl + bf;

                f32x4 st[4][2] = {};
                __builtin_amdgcn_s_setprio(1);
#pragma unroll
                for (int t = 0; t < 4; ++t) {
                    const bf16x8 k0 = *(const bf16x8*)(Klb + (t * 16 + l) * KLD + quad * 8);
                    const bf16x8 k1 = *(const bf16x8*)(Klb + (t * 16 + l) * KLD + 32 + quad * 8);
                    st[t][0] = MFMA16(k0, qb[0][0], st[t][0]);
                    st[t][0] = MFMA16(k1, qb[0][1], st[t][0]);
                    st[t][1] = MFMA16(k0, qb[1][0], st[t][1]);
                    st[t][1] = MFMA16(k1, qb[1][1], st[t][1]);
                }
                __builtin_amdgcn_s_setprio(0);
                if (c + 63 > q0w) {
#pragma unroll
                    for (int u = 0; u < 2; ++u) {
                        const int thr = q0w + u * 16 + l - c - quad * 4;
#pragma unroll
                        for (int t = 0; t < 4; ++t)
#pragma unroll
                            for (int r = 0; r < 4; ++r)
                                if (t * 16 + r > thr) st[t][u][r] = -3e38f;
                    }
                }
#pragma unroll
                for (int u = 0; u < 2; ++u) {
                    float cmax = -3e38f;
#pragma unroll
                    for (int t = 0; t < 4; ++t)
#pragma unroll
                        for (int r = 0; r < 4; ++r)
                            cmax = fmaxf(cmax, st[t][u][r]);
                    cmax = fmaxf(cmax, __shfl_xor(cmax, 16));
                    cmax = fmaxf(cmax, __shfl_xor(cmax, 32));
                    // defer-max (T13): skip O/l rescale while max growth <= 8;
                    // P bounded by e^8, fp32 accum has headroom.
                    if (!__all(cmax - m_run[u] <= 8.0f)) {
                        const float mnew  = fmaxf(m_run[u], cmax);
                        const float alpha = __expf(m_run[u] - mnew);
                        m_run[u] = mnew;
                        l_run[u] *= alpha;
#pragma unroll
                        for (int n = 0; n < 4; ++n)
#pragma unroll
                            for (int r = 0; r < 4; ++r)
                                o[n][u][r] *= alpha;
                    }
                    float csum = 0.f;
#pragma unroll
                    for (int t = 0; t < 4; ++t)
#pragma unroll
                        for (int r = 0; r < 4; ++r) {
                            st[t][u][r] = __expf(st[t][u][r] - m_run[u]);
                            csum += st[t][u][r];
                        }
                    csum += __shfl_xor(csum, 16);
                    csum += __shfl_xor(csum, 32);
                    l_run[u] += csum;
#pragma unroll
                    for (int t = 0; t < 4; ++t) {
                        bf16x4 pk;
                        pk[0] = (bf16_t)st[t][u][0]; pk[1] = (bf16_t)st[t][u][1];
                        pk[2] = (bf16_t)st[t][u][2]; pk[3] = (bf16_t)st[t][u][3];
                        *(bf16x4*)(Pw + (u * 16 + l) * KLD + t * 16 + quad * 4) = pk;
                    }
                }
                const bf16x8 pb00 = *(const bf16x8*)(Pw + l * KLD + quad * 8);
                const bf16x8 pb01 = *(const bf16x8*)(Pw + l * KLD + 32 + quad * 8);
                const bf16x8 pb10 = *(const bf16x8*)(Pw + (16 + l) * KLD + quad * 8);
                const bf16x8 pb11 = *(const bf16x8*)(Pw + (16 + l) * KLD + 32 + quad * 8);
                __builtin_amdgcn_s_setprio(1);
#pragma unroll
                for (int n = 0; n < 4; ++n) {
                    const bf16x8 v0 = *(const bf16x8*)(Vlb + (n * 16 + l) * KLD + quad * 8);
                    const bf16x8 v1 = *(const bf16x8*)(Vlb + (n * 16 + l) * KLD + 32 + quad * 8);
                    o[n][0] = MFMA16(v0, pb00, o[n][0]);
                    o[n][0] = MFMA16(v1, pb01, o[n][0]);
                    o[n][1] = MFMA16(v0, pb10, o[n][1]);
                    o[n][1] = MFMA16(v1, pb11, o[n][1]);
                }
                __builtin_amdgcn_s_setprio(0);
            }

            if (pf) {   // write next chunk into the other buffer
                *(bf16x8*)(Kl + bn + srow * KLD + sch)        = pk0;
                *(bf16x8*)(Kl + bn + (32 + srow) * KLD + sch) = pk1;
                *(bf16x8*)(Vl + bn + srow * KLD + sch)        = pv0;
                *(bf16x8*)(Vl + bn + (32 + srow) * KLD + sch) = pv1;
            }
            __syncthreads();
        }

#pragma unroll
        for (int u = 0; u < 2; ++u) {
            const float inv = 1.0f / l_run[u];
#pragma unroll
            for (int n = 0; n < 4; ++n) {
                bf16x4 ov;
                ov[0] = (bf16_t)(o[n][u][0] * inv); ov[1] = (bf16_t)(o[n][u][1] * inv);
                ov[2] = (bf16_t)(o[n][u][2] * inv); ov[3] = (bf16_t)(o[n][u][3] * inv);
                *(bf16x4*)(Pw + (u * 16 + l) * KLD + n * 16 + quad * 4) = ov;
            }
        }
        const int row  = lane >> 1;
        const int half = (lane & 1) * 32;
        const bf16x8 w0 = *(const bf16x8*)(Pw + row * KLD + half);
        const bf16x8 w1 = *(const bf16x8*)(Pw + row * KLD + half + 8);
        const bf16x8 w2 = *(const bf16x8*)(Pw + row * KLD + half + 16);
        const bf16x8 w3 = *(const bf16x8*)(Pw + row * KLD + half + 24);
        bf16_t* op = O + ((size_t)(b * SEQ + qblk * 128 + wave * 32 + row)) * DM
                       + h * DK + half;
        *(bf16x8*)(op)      = w0;
        *(bf16x8*)(op + 8)  = w1;
        *(bf16x8*)(op + 16) = w2;
        *(bf16x8*)(op + 24) = w3;
    }
}

// ---------------------------------------------------------------------------
extern "C" void kernel_launch(void* const* d_in, const int* in_sizes, int n_in,
                              void* d_out, int out_size, void* d_ws, size_t ws_size,
                              hipStream_t stream)
{
    const float* x  = (const float*)d_in[0];
    const float* Wq = (const float*)d_in[1];
    const float* Wk = (const float*)d_in[2];
    const float* Wv = (const float*)d_in[3];
    const float* Wo = (const float*)d_in[4];

    char* ws = (char*)d_ws;
    float2* rope = (float2*)ws;                        // 512 KiB
    const size_t TEN = (size_t)MROWS * DM;
    bf16_t* xb    = (bf16_t*)(ws + (1 << 19));
    bf16_t* Wqkvt = xb + TEN;                          // [3072][1024] concat
    bf16_t* Wot   = Wqkvt + 3 * (size_t)WEL;
    bf16_t* Qt    = Wot + WEL;
    bf16_t* Kt    = Qt + TEN;
    bf16_t* Vt    = Kt + TEN;
    bf16_t* Ot    = Vt + TEN;

    // fused preprocessing: cvt + 4x wtr + rope in one launch
    prep_kernel<<<12544, 256, 0, stream>>>(x, Wq, Wk, Wv, Wo,
                                           xb, Wqkvt, Wot, rope);

    // merged QKV: 32 mt x 12 nt of 256^2, 8-phase schedule
    gemm_qkv_kernel<<<32 * 12, 512, 0, stream>>>(xb, Wqkvt, Qt, Kt, Vt, rope);

    // grid (bh, qchunk): bid%8 = bh%8 -> per-XCD K/V locality
    attn_kernel<<<dim3(NB * NH, 8), 256, 0, stream>>>(Qt, Kt, Vt, Ot);

    // out: 64 mt x 4 nt of 128x256 = 256 blocks = one exact round
    gemm_out_kernel<<<64 * 4, 512, 0, stream>>>(Ot, Wot, (float*)d_out);
}